// Round 8
// baseline (1188.856 us; speedup 1.0000x reference)
//
#include <hip/hip_runtime.h>

#define NB 4096
#define NT 1024
#define NWAVE 2048   // total waves; each handles 2 batch elements

typedef float f2 __attribute__((ext_vector_type(2)));
typedef float f4 __attribute__((ext_vector_type(4)));

// Quad gate layout: lane = 4*q + g, g in {0:i, 1:f, 2:g~, 3:o}, q = hidden unit.
// After per-lane activation, broadcast the 4 gate values within each quad via DPP.
#define GATE(accv, creg, hout) {                                              \
    float e_ = __builtin_amdgcn_exp2f((accv) * kpre);                         \
    float r_ = __builtin_amdgcn_rcpf(1.0f + e_);                              \
    float a_ = fmaf(r_, kA, kB);                                              \
    int ai_ = __float_as_int(a_);                                             \
    float iv_ = __int_as_float(__builtin_amdgcn_mov_dpp(ai_, 0x00, 0xF, 0xF, 0)); \
    float fv_ = __int_as_float(__builtin_amdgcn_mov_dpp(ai_, 0x55, 0xF, 0xF, 0)); \
    float gv_ = __int_as_float(__builtin_amdgcn_mov_dpp(ai_, 0xAA, 0xF, 0xF, 0)); \
    float ov_ = __int_as_float(__builtin_amdgcn_mov_dpp(ai_, 0xFF, 0xF, 0xF, 0)); \
    creg = fmaf(fv_, creg, iv_ * gv_);                                        \
    float e2_ = __builtin_amdgcn_exp2f(creg * -2.88539008177792681f);         \
    float r2_ = __builtin_amdgcn_rcpf(1.0f + e2_);                            \
    hout = ov_ * fmaf(r2_, 2.0f, -1.0f);                                      \
}

#define HSUM4(v) (((v).x + (v).y) + ((v).z + (v).w))

// Correct LDS addressing: index ldsH[L][wv][p] directly (compile-time offsets).
#define HB(L, p, k) (*(const f4*)&ldsH[L][wv][p][4 * (k)])

// One layer-0 step for one batch slot p (0=A,1=B).
#define L0(p, x2, c, hn) {                                                    \
    f4 h0_ = HB(0, p, 0), h1_ = HB(0, p, 1), h2_ = HB(0, p, 2), h3_ = HB(0, p, 3); \
    f4 a0_ = wh0[0] * h0_;                                                    \
    f4 a1_ = wh0[1] * h1_;                                                    \
    a0_ = wh0[2] * h2_ + a0_;                                                 \
    a1_ = wh0[3] * h3_ + a1_;                                                 \
    a0_ = a0_ + a1_;                                                          \
    float acc_ = HSUM4(a0_) + fmaf(wi0.x, (x2).x, fmaf(wi0.y, (x2).y, bias0)); \
    GATE(acc_, c, hn);                                                        \
}

// One layer-L step (L=1,2) for slot p: dot(whL, h_L) + dot(wiL, h_{L-1} fresh).
#define LN(L, p, wh, wi, bias, c, hn) {                                       \
    f4 h0_ = HB(L, p, 0), h1_ = HB(L, p, 1), h2_ = HB(L, p, 2), h3_ = HB(L, p, 3); \
    f4 x0_ = HB((L) - 1, p, 0), x1_ = HB((L) - 1, p, 1);                      \
    f4 x2_ = HB((L) - 1, p, 2), x3_ = HB((L) - 1, p, 3);                      \
    f4 a0_ = wh[0] * h0_;                                                     \
    f4 a1_ = wh[1] * h1_;                                                     \
    f4 a2_ = wh[2] * h2_;                                                     \
    f4 a3_ = wh[3] * h3_;                                                     \
    a0_ = wi[0] * x0_ + a0_;                                                  \
    a1_ = wi[1] * x1_ + a1_;                                                  \
    a2_ = wi[2] * x2_ + a2_;                                                  \
    a3_ = wi[3] * x3_ + a3_;                                                  \
    a0_ = (a0_ + a1_) + (a2_ + a3_);                                          \
    float acc_ = HSUM4(a0_) + bias;                                           \
    GATE(acc_, c, hn);                                                        \
}

__global__ __launch_bounds__(256, 2) void lstm3_kernel(
    const float* __restrict__ x,
    const float* __restrict__ h0,
    const float* __restrict__ c0,
    const float* __restrict__ Wih0, const float* __restrict__ Whh0,
    const float* __restrict__ bih0, const float* __restrict__ bhh0,
    const float* __restrict__ Wih1, const float* __restrict__ Whh1,
    const float* __restrict__ bih1, const float* __restrict__ bhh1,
    const float* __restrict__ Wih2, const float* __restrict__ Whh2,
    const float* __restrict__ bih2, const float* __restrict__ bhh2,
    const float* __restrict__ Wfc,  const float* __restrict__ bfc,
    float* __restrict__ out)
{
    __shared__ float ldsH[3][4][2][16];   // [layer][wave][slot][unit]
    __shared__ float ldsX[4][2][64];      // [wave][slot][32 steps * 2]

    const int lane = threadIdx.x & 63;
    const int wv   = threadIdx.x >> 6;
    const int wg   = (blockIdx.x << 2) + wv;   // global wave id
    const int bA   = wg;                        // batch slot A
    const int bB   = wg + NWAVE;                // batch slot B
    const int q    = lane >> 2;        // hidden unit 0..15
    const int g    = lane & 3;         // gate 0:i 1:f 2:g 3:o
    const int row  = g * 16 + q;       // PyTorch gate-row index

    const float kpre = (g == 2) ? -2.88539008177792681f : -1.44269504088896340f;
    const float kA   = (g == 2) ? 2.0f : 1.0f;
    const float kB   = (g == 2) ? -1.0f : 0.0f;

    // ---- per-lane weight rows as f4 (shared by both batch slots) ----
    f2 wi0 = *(const f2*)&Wih0[row * 2];
    f4 wh0[4], wi1[4], wh1[4], wi2[4], wh2[4];
#pragma unroll
    for (int k = 0; k < 4; ++k) {
        wh0[k] = *(const f4*)&Whh0[row * 16 + 4 * k];
        wi1[k] = *(const f4*)&Wih1[row * 16 + 4 * k];
        wh1[k] = *(const f4*)&Whh1[row * 16 + 4 * k];
        wi2[k] = *(const f4*)&Wih2[row * 16 + 4 * k];
        wh2[k] = *(const f4*)&Whh2[row * 16 + 4 * k];
    }
    const float bias0 = bih0[row] + bhh0[row];
    const float bias1 = bih1[row] + bhh1[row];
    const float bias2 = bih2[row] + bhh2[row];

    // ---- initial state ----
    float cA0 = c0[0 * NB * 16 + bA * 16 + q];
    float cA1 = c0[1 * NB * 16 + bA * 16 + q];
    float cA2 = c0[2 * NB * 16 + bA * 16 + q];
    float cB0 = c0[0 * NB * 16 + bB * 16 + q];
    float cB1 = c0[1 * NB * 16 + bB * 16 + q];
    float cB2 = c0[2 * NB * 16 + bB * 16 + q];
    if (lane < 16) {
#pragma unroll
        for (int l = 0; l < 3; ++l) {
            ldsH[l][wv][0][lane] = h0[l * NB * 16 + bA * 16 + lane];
            ldsH[l][wv][1][lane] = h0[l * NB * 16 + bB * 16 + lane];
        }
    }
    __builtin_amdgcn_wave_barrier();

    const f2* __restrict__ xbA = (const f2*)&ldsX[wv][0][0];
    const f2* __restrict__ xbB = (const f2*)&ldsX[wv][1][0];

    // prefetch x chunk 0 for both slots
    const float* xgA = x + (size_t)bA * (NT * 2);
    const float* xgB = x + (size_t)bB * (NT * 2);
    float xpreA = xgA[lane];
    float xpreB = xgB[lane];

    for (int ch = 0; ch < (NT * 2) / 64; ++ch) {
        ldsX[wv][0][lane] = xpreA;
        ldsX[wv][1][lane] = xpreB;
        __builtin_amdgcn_wave_barrier();
        if (ch + 1 < (NT * 2) / 64) {
            xpreA = xgA[(ch + 1) * 64 + lane];
            xpreB = xgB[(ch + 1) * 64 + lane];
        }

#pragma unroll 1
        for (int s = 0; s < 32; ++s) {
            const f2 x2A = xbA[s];
            const f2 x2B = xbB[s];

            // ---- layer 0, both slots ----
            float hn0A, hn0B;
            L0(0, x2A, cA0, hn0A);
            L0(1, x2B, cB0, hn0B);
            if (g == 0) {
                ldsH[0][wv][0][q] = hn0A;
                ldsH[0][wv][1][q] = hn0B;
            }
            __builtin_amdgcn_wave_barrier();

            // ---- layer 1, both slots ----
            float hn1A, hn1B;
            LN(1, 0, wh1, wi1, bias1, cA1, hn1A);
            LN(1, 1, wh1, wi1, bias1, cB1, hn1B);
            if (g == 0) {
                ldsH[1][wv][0][q] = hn1A;
                ldsH[1][wv][1][q] = hn1B;
            }
            __builtin_amdgcn_wave_barrier();

            // ---- layer 2, both slots ----
            float hn2A, hn2B;
            LN(2, 0, wh2, wi2, bias2, cA2, hn2A);
            LN(2, 1, wh2, wi2, bias2, cB2, hn2B);
            if (g == 0) {
                ldsH[2][wv][0][q] = hn2A;
                ldsH[2][wv][1][q] = hn2B;
            }
            __builtin_amdgcn_wave_barrier();
        }
    }

    // ---- epilogue: out[b] = Wfc . h2[T-1] + bfc ----
    if (lane == 0) {
        float sA = bfc[0], sB = bfc[0];
#pragma unroll
        for (int k = 0; k < 16; ++k) {
            sA = fmaf(ldsH[2][wv][0][k], Wfc[k], sA);
            sB = fmaf(ldsH[2][wv][1][k], Wfc[k], sB);
        }
        out[bA] = sA;
        out[bB] = sB;
    }
}

extern "C" void kernel_launch(void* const* d_in, const int* in_sizes, int n_in,
                              void* d_out, int out_size, void* d_ws, size_t ws_size,
                              hipStream_t stream) {
    (void)in_sizes; (void)n_in; (void)d_ws; (void)ws_size; (void)out_size;
    const float* x    = (const float*)d_in[0];
    const float* h0   = (const float*)d_in[1];
    const float* c0   = (const float*)d_in[2];
    const float* Wih0 = (const float*)d_in[3];
    const float* Whh0 = (const float*)d_in[4];
    const float* bih0 = (const float*)d_in[5];
    const float* bhh0 = (const float*)d_in[6];
    const float* Wih1 = (const float*)d_in[7];
    const float* Whh1 = (const float*)d_in[8];
    const float* bih1 = (const float*)d_in[9];
    const float* bhh1 = (const float*)d_in[10];
    const float* Wih2 = (const float*)d_in[11];
    const float* Whh2 = (const float*)d_in[12];
    const float* bih2 = (const float*)d_in[13];
    const float* bhh2 = (const float*)d_in[14];
    const float* Wfc  = (const float*)d_in[15];
    const float* bfc  = (const float*)d_in[16];
    float* out = (float*)d_out;

    lstm3_kernel<<<NWAVE / 4, 256, 0, stream>>>(
        x, h0, c0, Wih0, Whh0, bih0, bhh0, Wih1, Whh1, bih1, bhh1,
        Wih2, Whh2, bih2, bhh2, Wfc, bfc, out);
}

// Round 10
// 1049.150 us; speedup vs baseline: 1.1332x; 1.1332x over previous
//
#include <hip/hip_runtime.h>

#define NB 4096
#define NT 1024

typedef float f2 __attribute__((ext_vector_type(2)));
typedef float f4 __attribute__((ext_vector_type(4)));

// Quad gate layout: lane = 4*q + g, g in {0:i, 1:f, 2:g~, 3:o}, q = hidden unit.
// After per-lane activation, broadcast the 4 gate values within each quad via DPP.
#define GATE(accv, creg, hout) {                                              \
    float e_ = __builtin_amdgcn_exp2f((accv) * kpre);                         \
    float r_ = __builtin_amdgcn_rcpf(1.0f + e_);                              \
    float a_ = fmaf(r_, kA, kB);                                              \
    int ai_ = __float_as_int(a_);                                             \
    float iv_ = __int_as_float(__builtin_amdgcn_mov_dpp(ai_, 0x00, 0xF, 0xF, 0)); \
    float fv_ = __int_as_float(__builtin_amdgcn_mov_dpp(ai_, 0x55, 0xF, 0xF, 0)); \
    float gv_ = __int_as_float(__builtin_amdgcn_mov_dpp(ai_, 0xAA, 0xF, 0xF, 0)); \
    float ov_ = __int_as_float(__builtin_amdgcn_mov_dpp(ai_, 0xFF, 0xF, 0xF, 0)); \
    creg = fmaf(fv_, creg, iv_ * gv_);                                        \
    float e2_ = __builtin_amdgcn_exp2f(creg * -2.88539008177792681f);         \
    float r2_ = __builtin_amdgcn_rcpf(1.0f + e2_);                            \
    hout = ov_ * fmaf(r2_, 2.0f, -1.0f);                                      \
}

// Scalar (VOP3 v_fma_f32) dot over one 16-float LDS vector, 4 parallel chains.
// W_ = f4[4] weights (AGPR-parkable, scalar component reads), h0_..h3_ from LDS.
#define DOT16_INIT(W_, h0_, h1_, h2_, h3_, c0_, c1_, c2_, c3_) {              \
    c0_ = (W_)[0].x * (h0_).x;                                                \
    c1_ = (W_)[0].y * (h0_).y;                                                \
    c2_ = (W_)[0].z * (h0_).z;                                                \
    c3_ = (W_)[0].w * (h0_).w;                                                \
    c0_ = fmaf((W_)[1].x, (h1_).x, c0_);                                      \
    c1_ = fmaf((W_)[1].y, (h1_).y, c1_);                                      \
    c2_ = fmaf((W_)[1].z, (h1_).z, c2_);                                      \
    c3_ = fmaf((W_)[1].w, (h1_).w, c3_);                                      \
    c0_ = fmaf((W_)[2].x, (h2_).x, c0_);                                      \
    c1_ = fmaf((W_)[2].y, (h2_).y, c1_);                                      \
    c2_ = fmaf((W_)[2].z, (h2_).z, c2_);                                      \
    c3_ = fmaf((W_)[2].w, (h2_).w, c3_);                                      \
    c0_ = fmaf((W_)[3].x, (h3_).x, c0_);                                      \
    c1_ = fmaf((W_)[3].y, (h3_).y, c1_);                                      \
    c2_ = fmaf((W_)[3].z, (h3_).z, c2_);                                      \
    c3_ = fmaf((W_)[3].w, (h3_).w, c3_);                                      \
}

#define DOT16_ACC(W_, h0_, h1_, h2_, h3_, c0_, c1_, c2_, c3_) {               \
    c0_ = fmaf((W_)[0].x, (h0_).x, c0_);                                      \
    c1_ = fmaf((W_)[0].y, (h0_).y, c1_);                                      \
    c2_ = fmaf((W_)[0].z, (h0_).z, c2_);                                      \
    c3_ = fmaf((W_)[0].w, (h0_).w, c3_);                                      \
    c0_ = fmaf((W_)[1].x, (h1_).x, c0_);                                      \
    c1_ = fmaf((W_)[1].y, (h1_).y, c1_);                                      \
    c2_ = fmaf((W_)[1].z, (h1_).z, c2_);                                      \
    c3_ = fmaf((W_)[1].w, (h1_).w, c3_);                                      \
    c0_ = fmaf((W_)[2].x, (h2_).x, c0_);                                      \
    c1_ = fmaf((W_)[2].y, (h2_).y, c1_);                                      \
    c2_ = fmaf((W_)[2].z, (h2_).z, c2_);                                      \
    c3_ = fmaf((W_)[2].w, (h2_).w, c3_);                                      \
    c0_ = fmaf((W_)[3].x, (h3_).x, c0_);                                      \
    c1_ = fmaf((W_)[3].y, (h3_).y, c1_);                                      \
    c2_ = fmaf((W_)[3].z, (h3_).z, c2_);                                      \
    c3_ = fmaf((W_)[3].w, (h3_).w, c3_);                                      \
}

__global__ __launch_bounds__(256, 4) void lstm3_kernel(
    const float* __restrict__ x,
    const float* __restrict__ h0,
    const float* __restrict__ c0,
    const float* __restrict__ Wih0, const float* __restrict__ Whh0,
    const float* __restrict__ bih0, const float* __restrict__ bhh0,
    const float* __restrict__ Wih1, const float* __restrict__ Whh1,
    const float* __restrict__ bih1, const float* __restrict__ bhh1,
    const float* __restrict__ Wih2, const float* __restrict__ Whh2,
    const float* __restrict__ bih2, const float* __restrict__ bhh2,
    const float* __restrict__ Wfc,  const float* __restrict__ bfc,
    float* __restrict__ out)
{
    __shared__ float ldsH[3][4][16];   // h vectors, slot j = h[j], per wave
    __shared__ float ldsX[4][64];      // x staging: 32 steps * 2 floats per wave

    const int lane = threadIdx.x & 63;
    const int wv   = threadIdx.x >> 6;
    const int b    = (blockIdx.x << 2) + wv;
    const int q    = lane >> 2;        // hidden unit 0..15
    const int g    = lane & 3;         // gate 0:i 1:f 2:g 3:o
    const int row  = g * 16 + q;       // PyTorch gate-row index

    const float kpre = (g == 2) ? -2.88539008177792681f : -1.44269504088896340f;
    const float kA   = (g == 2) ? 2.0f : 1.0f;
    const float kB   = (g == 2) ? -1.0f : 0.0f;

    // ---- per-lane weight rows as f4 loads; components consumed ONLY by
    //      scalar VOP3 fma (AGPR-direct-sourceable) ----
    f2 wi0 = *(const f2*)&Wih0[row * 2];
    f4 wh0[4], wi1[4], wh1[4], wi2[4], wh2[4];
#pragma unroll
    for (int k = 0; k < 4; ++k) {
        wh0[k] = *(const f4*)&Whh0[row * 16 + 4 * k];
        wi1[k] = *(const f4*)&Wih1[row * 16 + 4 * k];
        wh1[k] = *(const f4*)&Whh1[row * 16 + 4 * k];
        wi2[k] = *(const f4*)&Wih2[row * 16 + 4 * k];
        wh2[k] = *(const f4*)&Whh2[row * 16 + 4 * k];
    }
    const float bias0 = bih0[row] + bhh0[row];
    const float bias1 = bih1[row] + bhh1[row];
    const float bias2 = bih2[row] + bhh2[row];

    // ---- initial state ----
    float c0r = c0[0 * NB * 16 + b * 16 + q];
    float c1r = c0[1 * NB * 16 + b * 16 + q];
    float c2r = c0[2 * NB * 16 + b * 16 + q];
    if (lane < 16) {
        ldsH[0][wv][lane] = h0[0 * NB * 16 + b * 16 + lane];
        ldsH[1][wv][lane] = h0[1 * NB * 16 + b * 16 + lane];
        ldsH[2][wv][lane] = h0[2 * NB * 16 + b * 16 + lane];
    }
    __builtin_amdgcn_wave_barrier();

    const f4* __restrict__ hb0 = (const f4*)&ldsH[0][wv][0];
    const f4* __restrict__ hb1 = (const f4*)&ldsH[1][wv][0];
    const f4* __restrict__ hb2 = (const f4*)&ldsH[2][wv][0];
    const f2* __restrict__ xb  = (const f2*)&ldsX[wv][0];

    // prefetch x chunk 0 (64 floats = 32 timesteps * 2 comps)
    float xpre = x[(size_t)b * (NT * 2) + lane];

    for (int ch = 0; ch < (NT * 2) / 64; ++ch) {
        ldsX[wv][lane] = xpre;
        __builtin_amdgcn_wave_barrier();
        if (ch + 1 < (NT * 2) / 64)
            xpre = x[(size_t)b * (NT * 2) + (ch + 1) * 64 + lane];

#pragma unroll 1
        for (int s = 0; s < 32; ++s) {
            const f2 x2 = xb[s];

            // ================= layer 0 =================
            {
                f4 ha = hb0[0], hc = hb0[1], hd = hb0[2], he = hb0[3];
                float d0, d1, d2, d3;
                DOT16_INIT(wh0, ha, hc, hd, he, d0, d1, d2, d3);
                d0 = fmaf(wi0.x, x2.x, d0);
                d1 = fmaf(wi0.y, x2.y, d1);
                d2 += bias0;
                float acc = (d0 + d1) + (d2 + d3);
                float hn0;
                GATE(acc, c0r, hn0);
                if (g == 0) ldsH[0][wv][q] = hn0;
            }
            __builtin_amdgcn_wave_barrier();

            // ================= layer 1 =================
            {
                f4 ha = hb1[0], hc = hb1[1], hd = hb1[2], he = hb1[3];
                f4 xa = hb0[0], xc = hb0[1], xd = hb0[2], xe = hb0[3];
                float d0, d1, d2, d3;
                DOT16_INIT(wh1, ha, hc, hd, he, d0, d1, d2, d3);
                DOT16_ACC(wi1, xa, xc, xd, xe, d0, d1, d2, d3);
                d2 += bias1;
                float acc = (d0 + d1) + (d2 + d3);
                float hn1;
                GATE(acc, c1r, hn1);
                if (g == 0) ldsH[1][wv][q] = hn1;
            }
            __builtin_amdgcn_wave_barrier();

            // ================= layer 2 =================
            {
                f4 ha = hb2[0], hc = hb2[1], hd = hb2[2], he = hb2[3];
                f4 xa = hb1[0], xc = hb1[1], xd = hb1[2], xe = hb1[3];
                float d0, d1, d2, d3;
                DOT16_INIT(wh2, ha, hc, hd, he, d0, d1, d2, d3);
                DOT16_ACC(wi2, xa, xc, xd, xe, d0, d1, d2, d3);
                d2 += bias2;
                float acc = (d0 + d1) + (d2 + d3);
                float hn2;
                GATE(acc, c2r, hn2);
                if (g == 0) ldsH[2][wv][q] = hn2;
            }
            __builtin_amdgcn_wave_barrier();
        }
    }

    // ---- epilogue: out[b] = Wfc . h2[T-1] + bfc ----
    if (lane == 0) {
        float s = bfc[0];
#pragma unroll
        for (int k = 0; k < 16; ++k) s = fmaf(ldsH[2][wv][k], Wfc[k], s);
        out[b] = s;
    }
}

extern "C" void kernel_launch(void* const* d_in, const int* in_sizes, int n_in,
                              void* d_out, int out_size, void* d_ws, size_t ws_size,
                              hipStream_t stream) {
    (void)in_sizes; (void)n_in; (void)d_ws; (void)ws_size; (void)out_size;
    const float* x    = (const float*)d_in[0];
    const float* h0   = (const float*)d_in[1];
    const float* c0   = (const float*)d_in[2];
    const float* Wih0 = (const float*)d_in[3];
    const float* Whh0 = (const float*)d_in[4];
    const float* bih0 = (const float*)d_in[5];
    const float* bhh0 = (const float*)d_in[6];
    const float* Wih1 = (const float*)d_in[7];
    const float* Whh1 = (const float*)d_in[8];
    const float* bih1 = (const float*)d_in[9];
    const float* bhh1 = (const float*)d_in[10];
    const float* Wih2 = (const float*)d_in[11];
    const float* Whh2 = (const float*)d_in[12];
    const float* bih2 = (const float*)d_in[13];
    const float* bhh2 = (const float*)d_in[14];
    const float* Wfc  = (const float*)d_in[15];
    const float* bfc  = (const float*)d_in[16];
    float* out = (float*)d_out;

    lstm3_kernel<<<NB / 4, 256, 0, stream>>>(
        x, h0, c0, Wih0, Whh0, bih0, bhh0, Wih1, Whh1, bih1, bhh1,
        Wih2, Whh2, bih2, bhh2, Wfc, bfc, out);
}